// Round 5
// baseline (12869.801 us; speedup 1.0000x reference)
//
#include <hip/hip_runtime.h>
#include <math.h>

// ---------------------------------------------------------------------------
// Bert_BiLstm_Crf: 2-layer BiLSTM (B=64,T=512,D=768,H=384/dir) -> FC(30) -> Viterbi
// Round 5: tagged {h,step} publish (data-as-flag, 8B-atomic pairs) removes the
// 3-round-trip sync chain; z-merged GEMM/FC dispatches.
// ---------------------------------------------------------------------------

#define B_    64
#define T_    512
#define D_    768
#define H_    384
#define G4    1536
#define NTAGS 30
#define TC    64
#define NCH   (T_ / TC)     // 8

typedef float f32x4 __attribute__((ext_vector_type(4)));
typedef float f32x2 __attribute__((ext_vector_type(2)));

__device__ __forceinline__ float sigm(float x) { return 1.f / (1.f + expf(-x)); }

// ------------- chunk GEMM (z picks fwd/bwd): pre = A_chunk @ W^T + b1 + b2 --
__global__ __launch_bounds__(256)
void sgemm_pre(const float* __restrict__ A, int t0f, int t0b,
               const float* __restrict__ Wf, const float* __restrict__ Wb,
               const float* __restrict__ b1f, const float* __restrict__ b2f,
               const float* __restrict__ b1b, const float* __restrict__ b2b,
               float* __restrict__ outF, float* __restrict__ outB) {
  const int z = blockIdx.z;
  const int t0 = z ? t0b : t0f;
  const float* __restrict__ W  = z ? Wb  : Wf;
  const float* __restrict__ b1 = z ? b1b : b1f;
  const float* __restrict__ b2 = z ? b2b : b2f;
  float* __restrict__ Cc = z ? outB : outF;

  __shared__ float As[16][128];
  __shared__ float Bs[16][128];
  const int tid = threadIdx.x;
  const int bm = blockIdx.y * 128;
  const int bn = blockIdx.x * 128;
  const int tx = tid & 15;
  const int ty = tid >> 4;

  float acc[8][8];
  #pragma unroll
  for (int i = 0; i < 8; ++i)
    #pragma unroll
    for (int j = 0; j < 8; ++j) acc[i][j] = 0.f;

  for (int k0 = 0; k0 < D_; k0 += 16) {
    #pragma unroll
    for (int s = tid; s < 512; s += 256) {
      int r = s >> 2, k4 = (s & 3) * 4;
      int rl = bm + r;
      const float* arow = A + ((size_t)(rl >> 6) * T_ + t0 + (rl & 63)) * D_;
      float4 va = *(const float4*)(arow + k0 + k4);
      As[k4 + 0][r] = va.x; As[k4 + 1][r] = va.y;
      As[k4 + 2][r] = va.z; As[k4 + 3][r] = va.w;
      float4 vb = *(const float4*)(W + (size_t)(bn + r) * D_ + k0 + k4);
      Bs[k4 + 0][r] = vb.x; Bs[k4 + 1][r] = vb.y;
      Bs[k4 + 2][r] = vb.z; Bs[k4 + 3][r] = vb.w;
    }
    __syncthreads();
    #pragma unroll
    for (int k = 0; k < 16; ++k) {
      float a[8], bv[8];
      *(float4*)(a)      = *(const float4*)&As[k][ty * 4];
      *(float4*)(a + 4)  = *(const float4*)&As[k][64 + ty * 4];
      *(float4*)(bv)     = *(const float4*)&Bs[k][tx * 4];
      *(float4*)(bv + 4) = *(const float4*)&Bs[k][64 + tx * 4];
      #pragma unroll
      for (int i = 0; i < 8; ++i)
        #pragma unroll
        for (int j = 0; j < 8; ++j)
          acc[i][j] += a[i] * bv[j];
    }
    __syncthreads();
  }

  float4 b1l = *(const float4*)(b1 + bn + tx * 4);
  float4 b2l = *(const float4*)(b2 + bn + tx * 4);
  float4 b1h = *(const float4*)(b1 + bn + 64 + tx * 4);
  float4 b2h = *(const float4*)(b2 + bn + 64 + tx * 4);
  float4 bl = {b1l.x + b2l.x, b1l.y + b2l.y, b1l.z + b2l.z, b1l.w + b2l.w};
  float4 bh = {b1h.x + b2h.x, b1h.y + b2h.y, b1h.z + b2h.z, b1h.w + b2h.w};

  #pragma unroll
  for (int i = 0; i < 8; ++i) {
    int r = (i < 4) ? (ty * 4 + i) : (64 + ty * 4 + (i - 4));
    size_t row = (size_t)(bm + r);
    float4 lo = {acc[i][0] + bl.x, acc[i][1] + bl.y, acc[i][2] + bl.z, acc[i][3] + bl.w};
    float4 hi = {acc[i][4] + bh.x, acc[i][5] + bh.y, acc[i][6] + bh.z, acc[i][7] + bh.w};
    *(float4*)(Cc + row * G4 + bn + tx * 4)      = lo;
    *(float4*)(Cc + row * G4 + bn + 64 + tx * 4) = hi;
  }
}

// ---------------- persistent-W LSTM recurrence chunk ------------------------
// grid 256: stream = bid&7, wg = bid>>3. WG owns 12 hidden units, W in VGPRs.
// Cross-WG h exchange: tagged {h, (float)seq} pairs, 8B-atomic dwordx2 stores
// (sc0 sc1), readers poll data+tags directly (no separate flag round trip).
template<int LAYER>
__global__ __launch_bounds__(256, 1)
void lstm_chunk(const float* __restrict__ preF, const float* __restrict__ preB,
                const float* __restrict__ whhF, const float* __restrict__ whhB,
                float* __restrict__ hbuf, float* __restrict__ h2cF, float* __restrict__ h2cB,
                float* __restrict__ hpairs, float* __restrict__ c_g,
                int chunk, unsigned seqBase) {
  const int bid    = blockIdx.x;
  const int stream = bid & 7;
  const int wg     = bid >> 3;          // 0..31
  const int dir    = stream & 1;
  const int bg     = stream >> 1;       // 0..3
  const int tid    = threadIdx.x;
  const int g      = tid >> 6;          // gate 0..3
  const int lane   = tid & 63;
  const int kg     = lane & 15;         // k-slice id (24 k each)
  const int uq     = lane >> 4;         // 0..3

  const float* __restrict__ pre = dir ? preB : preF;
  const float* __restrict__ whh = dir ? whhB : whhF;

  __shared__ float h_lds[16 * 448];     // [b][16 slices * 28]
  __shared__ float gLDS[4 * 192];       // [gate][u*16+b]
  __shared__ float lds_pad[12800];      // force 1 WG/CU

  if (__float_as_uint(c_g[0]) == 0xDEADBEEFu) lds_pad[tid] = 1.f;  // keep pad

  // ---- W block in registers: rows g*384 + wg*12 + uq*3 + {0,1,2}, k = kg*24.. ----
  float4 W[3][6];
  {
    const float* wsrc = whh + ((size_t)(g * H_ + wg * 12 + uq * 3)) * H_ + kg * 24;
    #pragma unroll
    for (int i = 0; i < 3; ++i)
      #pragma unroll
      for (int jj = 0; jj < 6; ++jj)
        W[i][jj] = *(const float4*)(wsrc + (size_t)i * H_ + jj * 4);
  }

  const int own_u = tid % 12;
  const int own_b = tid / 12;
  float c_own = 0.f;
  if (chunk > 0 && tid < 192)
    c_own = c_g[(((size_t)stream * 32 + wg) * 12 + own_u) * 16 + own_b];

  // tagged pair buffers: [parity][stream][b*384+k] pairs of {h, tag}
  float* hp0 = hpairs + (size_t)stream * 12288;
  float* hp1 = hpairs + (size_t)(8 + stream) * 12288;

  // per-thread poll slice: float4-chunks c4 = tid + i*256, i<12 (2 pairs each)
  // pair p = 2*c4 (+1): b = p/384, k = p%384 -> h_lds[b*448 + (k/24)*28 + k%24]
  int ldsoff[12];
  #pragma unroll
  for (int i = 0; i < 12; ++i) {
    int c4 = tid + i * 256;
    int p  = 2 * c4;
    int b  = p / 384, k = p % 384;
    ldsoff[i] = b * 448 + (k / 24) * 28 + (k % 24);
  }

  // ---- init h_lds ----
  if (chunk == 0) {
    for (int i = tid; i < 16 * 448; i += 256) h_lds[i] = 0.f;
  } else {
    const float ftag = (float)(int)seqBase;    // written by prev launch's last step
    f32x4 v[12];
    bool done = false;
    while (!done) {
      #pragma unroll
      for (int i = 0; i < 12; ++i)
        asm volatile("global_load_dwordx4 %0, %1, off sc0 sc1"
                     : "=v"(v[i]) : "v"(hp0 + (size_t)(tid + i * 256) * 4) : "memory");
      asm volatile("s_waitcnt vmcnt(0)" ::: "memory");
      done = true;
      #pragma unroll
      for (int i = 0; i < 12; ++i) done = done && (v[i].y == ftag) && (v[i].w == ftag);
      if (!done) __builtin_amdgcn_s_sleep(1);
    }
    #pragma unroll
    for (int i = 0; i < 12; ++i)
      *(f32x2*)&h_lds[ldsoff[i]] = f32x2{v[i].x, v[i].z};
  }
  __syncthreads();

  const int ucol = wg * 12;

  for (int s = 0; s < TC; ++s) {
    const int t  = dir ? (T_ - 1 - chunk * TC - s) : (chunk * TC + s);
    const int lt = dir ? (TC - 1 - s) : s;

    // ---- prefetch pre-activation early ----
    float pv0, pv1, pv2;
    {
      const size_t prow = ((size_t)(bg * 16 + kg) * TC + lt) * G4 + g * H_ + ucol + uq * 3;
      pv0 = pre[prow]; pv1 = pre[prow + 1]; pv2 = pre[prow + 2];
    }

    // ---- matvec over this thread's k-slice ----
    float acc[3][16];
    #pragma unroll
    for (int i = 0; i < 3; ++i)
      #pragma unroll
      for (int b = 0; b < 16; ++b) acc[i][b] = 0.f;

    const int hcol = kg * 28;
    #pragma unroll
    for (int kq = 0; kq < 6; ++kq) {
      #pragma unroll
      for (int b4 = 0; b4 < 4; ++b4) {
        float4 h4[4];
        #pragma unroll
        for (int bb = 0; bb < 4; ++bb)
          h4[bb] = *(const float4*)&h_lds[(b4 * 4 + bb) * 448 + hcol + kq * 4];
        #pragma unroll
        for (int i = 0; i < 3; ++i) {
          float4 w4 = W[i][kq];
          #pragma unroll
          for (int bb = 0; bb < 4; ++bb)
            acc[i][b4 * 4 + bb] += w4.x * h4[bb].x + w4.y * h4[bb].y
                                 + w4.z * h4[bb].z + w4.w * h4[bb].w;
        }
      }
    }

    // ---- butterfly reduce over the 16 kg lanes; lane kg keeps batch kg ----
    float red[3];
    #pragma unroll
    for (int i = 0; i < 3; ++i) {
      int n = 16;
      #pragma unroll
      for (int mask = 8; mask >= 1; mask >>= 1) {
        n >>= 1;
        const bool up = (kg & mask) != 0;
        #pragma unroll
        for (int j = 0; j < n; ++j) {
          float send = up ? acc[i][j] : acc[i][j + n];
          float recv = __shfl_xor(send, mask, 64);
          acc[i][j] = (up ? acc[i][j + n] : acc[i][j]) + recv;
        }
      }
      red[i] = acc[i][0];
    }

    // ---- add pre, exchange gates through LDS ----
    gLDS[g * 192 + (uq * 3 + 0) * 16 + kg] = red[0] + pv0;
    gLDS[g * 192 + (uq * 3 + 1) * 16 + kg] = red[1] + pv1;
    gLDS[g * 192 + (uq * 3 + 2) * 16 + kg] = red[2] + pv2;
    __syncthreads();

    const float ftag = (float)(int)(seqBase + (unsigned)s + 1u);
    float* hp_w = ((s + 1) & 1) ? hp1 : hp0;

    // ---- nonlinearity + tagged publish ----
    if (tid < 192) {
      float gi = sigm(gLDS[0 * 192 + own_u * 16 + own_b]);
      float gf = sigm(gLDS[1 * 192 + own_u * 16 + own_b]);
      float gg = tanhf(gLDS[2 * 192 + own_u * 16 + own_b]);
      float go = sigm(gLDS[3 * 192 + own_u * 16 + own_b]);
      c_own = gf * c_own + gi * gg;
      float h_new = go * tanhf(c_own);

      const int bglob = bg * 16 + own_b;
      if (LAYER == 0) {
        hbuf[((size_t)bglob * T_ + t) * 768 + dir * H_ + ucol + own_u] = h_new;
      } else {
        float* o = dir ? h2cB : h2cF;
        o[((size_t)bglob * TC + lt) * H_ + ucol + own_u] = h_new;
      }
      f32x2 pv = {h_new, ftag};
      asm volatile("global_store_dwordx2 %0, %1, off sc0 sc1"
                   :: "v"(hp_w + (size_t)(own_b * 384 + ucol + own_u) * 2), "v"(pv)
                   : "memory");
    }
    if (s == TC - 1) break;     // next launch polls these tags

    // ---- poll all tagged pairs of this step, refill h_lds ----
    {
      f32x4 v[12];
      bool done = false;
      while (!done) {
        #pragma unroll
        for (int i = 0; i < 12; ++i)
          asm volatile("global_load_dwordx4 %0, %1, off sc0 sc1"
                       : "=v"(v[i]) : "v"(hp_w + (size_t)(tid + i * 256) * 4) : "memory");
        asm volatile("s_waitcnt vmcnt(0)" ::: "memory");
        done = true;
        #pragma unroll
        for (int i = 0; i < 12; ++i) done = done && (v[i].y == ftag) && (v[i].w == ftag);
        if (!done) __builtin_amdgcn_s_sleep(1);
      }
      #pragma unroll
      for (int i = 0; i < 12; ++i)
        *(f32x2*)&h_lds[ldsoff[i]] = f32x2{v[i].x, v[i].z};
    }
    __syncthreads();
  }

  if (tid < 192)
    c_g[(((size_t)stream * 32 + wg) * 12 + own_u) * 16 + own_b] = c_own;
}

// ---------------- feats init: feats[row][n] = fc_b[n] ------------------------
__global__ __launch_bounds__(256)
void feats_init(const float* __restrict__ fc_b, float* __restrict__ feats) {
  const int n = threadIdx.x & 31;
  const size_t row = (size_t)blockIdx.x * 8 + (threadIdx.x >> 5);
  if (n >= NTAGS) return;
  feats[row * NTAGS + n] = fc_b[n];
}

// -------- half-FC accumulate (z picks fwd/bwd): feats += h2c @ fc_w_half^T ---
__global__ __launch_bounds__(256)
void fc_half(const float* __restrict__ h2cF, const float* __restrict__ h2cB,
             const float* __restrict__ fc_w,
             float* __restrict__ feats, int t0f, int t0b) {
  const int z = blockIdx.z;
  const float* __restrict__ h2c = z ? h2cB : h2cF;
  const int coff = z ? H_ : 0;
  const int t0   = z ? t0b : t0f;

  const int tid = threadIdx.x;
  const int n  = tid & 31;
  const int rl = tid >> 5;
  const int row_loc = blockIdx.x * 8 + rl;     // 0..4095
  if (n >= NTAGS) return;
  const int b  = row_loc >> 6;
  const int lt = row_loc & 63;
  const float* x = h2c + (size_t)row_loc * H_;
  const float* w = fc_w + (size_t)n * D_ + coff;
  float acc = 0.f;
  #pragma unroll 8
  for (int k = 0; k < H_; k += 4) {
    float4 xv = *(const float4*)(x + k);
    float4 wv = *(const float4*)(w + k);
    acc += xv.x * wv.x + xv.y * wv.y + xv.z * wv.z + xv.w * wv.w;
  }
  feats[((size_t)b * T_ + t0 + lt) * NTAGS + n] += acc;
}

// ---------------- Viterbi: one wave per batch element -----------------------
__global__ __launch_bounds__(64)
void viterbi_kernel(const float* __restrict__ feats,
                    const float* __restrict__ trans,
                    float* __restrict__ score_out, float* __restrict__ path_out) {
  const int b = blockIdx.x;
  const int lane = threadIdx.x;
  __shared__ float trs[NTAGS * NTAGS];
  __shared__ float ld[32];
  __shared__ unsigned char psi[T_ - 1][NTAGS];

  for (int i = lane; i < NTAGS * NTAGS; i += 64) trs[i] = trans[i];
  if (lane < NTAGS) ld[lane] = -10000.0f;
  __syncthreads();

  for (int t = 1; t < T_; ++t) {
    float best = -INFINITY; int arg = 0;
    if (lane < NTAGS) {
      #pragma unroll
      for (int p = 0; p < NTAGS; ++p) {
        float v = trs[lane * NTAGS + p] + ld[p];
        if (v > best) { best = v; arg = p; }   // first-occurrence argmax
      }
    }
    __syncthreads();
    if (lane < NTAGS) {
      ld[lane] = best + feats[((size_t)b * T_ + t) * NTAGS + lane];
      psi[t - 1][lane] = (unsigned char)arg;
    }
    __syncthreads();
  }

  if (lane == 0) {
    float best = ld[0]; int last = 0;
    #pragma unroll
    for (int p = 1; p < NTAGS; ++p)
      if (ld[p] > best) { best = ld[p]; last = p; }
    score_out[b] = best;
    int tag = last;
    path_out[(size_t)b * T_ + (T_ - 1)] = (float)tag;
    for (int t = T_ - 2; t >= 0; --t) {
      tag = psi[t][tag];
      path_out[(size_t)b * T_ + t] = (float)tag;
    }
  }
}

// ---------------------------------------------------------------------------
extern "C" void kernel_launch(void* const* d_in, const int* in_sizes, int n_in,
                              void* d_out, int out_size, void* d_ws, size_t ws_size,
                              hipStream_t stream) {
  const float* embeds = (const float*)d_in[0];
  const float* trans  = (const float*)d_in[1];
  const float* fc_w   = (const float*)d_in[2];
  const float* fc_b   = (const float*)d_in[3];
  const float* w_ih[2][2] = {{(const float*)d_in[4],  (const float*)d_in[8]},
                             {(const float*)d_in[12], (const float*)d_in[16]}};
  const float* w_hh[2][2] = {{(const float*)d_in[5],  (const float*)d_in[9]},
                             {(const float*)d_in[13], (const float*)d_in[17]}};
  const float* b_ih[2][2] = {{(const float*)d_in[6],  (const float*)d_in[10]},
                             {(const float*)d_in[14], (const float*)d_in[18]}};
  const float* b_hh[2][2] = {{(const float*)d_in[7],  (const float*)d_in[11]},
                             {(const float*)d_in[15], (const float*)d_in[19]}};

  const size_t HB   = (size_t)B_ * T_ * 768;     // 25,165,824 (h1)
  const size_t PRE  = (size_t)B_ * TC * G4;      //  6,291,456 each
  const size_t H2C  = (size_t)B_ * TC * H_;      //  1,572,864 each
  const size_t FT   = (size_t)B_ * T_ * NTAGS;   //    983,040
  const size_t HP   = (size_t)2 * 8 * 6144 * 2;  //    196,608 (tagged pairs)
  const size_t CG   = (size_t)8 * 32 * 12 * 16;  //     49,152

  float* ws     = (float*)d_ws;
  float* hbuf   = ws;
  float* preF   = hbuf + HB;
  float* preB   = preF + PRE;
  float* h2cF   = preB + PRE;
  float* h2cB   = h2cF + H2C;
  float* feats  = h2cB + H2C;
  float* hpairs = feats + FT;
  float* c_g    = hpairs + HP;

  feats_init<<<(B_ * T_) / 8, 256, 0, stream>>>(fc_b, feats);

  dim3 gg(G4 / 128, (B_ * TC) / 128, 2);         // (12, 32, 2) = 768 WGs

  // -------- layer 0 --------
  for (int c = 0; c < NCH; ++c) {
    const int t0f = c * TC;
    const int t0b = T_ - (c + 1) * TC;
    sgemm_pre<<<gg, 256, 0, stream>>>(embeds, t0f, t0b, w_ih[0][0], w_ih[0][1],
                                      b_ih[0][0], b_hh[0][0], b_ih[0][1], b_hh[0][1],
                                      preF, preB);
    lstm_chunk<0><<<256, 256, 0, stream>>>(preF, preB, w_hh[0][0], w_hh[0][1],
                                           hbuf, nullptr, nullptr, hpairs, c_g,
                                           c, (unsigned)(c * TC));
  }

  // -------- layer 1 (+ per-chunk half-FC) --------
  for (int c = 0; c < NCH; ++c) {
    const int t0f = c * TC;
    const int t0b = T_ - (c + 1) * TC;
    sgemm_pre<<<gg, 256, 0, stream>>>(hbuf, t0f, t0b, w_ih[1][0], w_ih[1][1],
                                      b_ih[1][0], b_hh[1][0], b_ih[1][1], b_hh[1][1],
                                      preF, preB);
    lstm_chunk<1><<<256, 256, 0, stream>>>(preF, preB, w_hh[1][0], w_hh[1][1],
                                           nullptr, h2cF, h2cB, hpairs, c_g,
                                           c, (unsigned)(T_ + c * TC));
    dim3 gf((B_ * TC) / 8, 1, 2);
    fc_half<<<gf, 256, 0, stream>>>(h2cF, h2cB, fc_w, feats, t0f, t0b);
  }

  // -------- Viterbi -> d_out = [score(64) | path(64*512) as float] --------
  float* score = (float*)d_out;
  float* path  = score + B_;
  viterbi_kernel<<<B_, 64, 0, stream>>>(feats, trans, score, path);
}

// Round 7
// 11293.661 us; speedup vs baseline: 1.1396x; 1.1396x over previous
//
#include <hip/hip_runtime.h>
#include <math.h>

// ---------------------------------------------------------------------------
// Bert_BiLstm_Crf: 2-layer BiLSTM (B=64,T=512,D=768,H=384/dir) -> FC(30) -> Viterbi
// Round 7: round-4 verified sync semantics (sc0 sc1 + flags) with P/Q batch-half
// software pipelining inside lstm_chunk to hide IC round-trip latency.
// ---------------------------------------------------------------------------

#define B_    64
#define T_    512
#define D_    768
#define H_    384
#define G4    1536
#define NTAGS 30
#define TC    64
#define NCH   (T_ / TC)     // 8

typedef float f32x4 __attribute__((ext_vector_type(4)));

__device__ __forceinline__ float sigm(float x) { return 1.f / (1.f + expf(-x)); }

// ------------- chunk GEMM (z picks fwd/bwd): pre = A_chunk @ W^T + b1 + b2 --
__global__ __launch_bounds__(256)
void sgemm_pre(const float* __restrict__ A, int t0f, int t0b,
               const float* __restrict__ Wf, const float* __restrict__ Wb,
               const float* __restrict__ b1f, const float* __restrict__ b2f,
               const float* __restrict__ b1b, const float* __restrict__ b2b,
               float* __restrict__ outF, float* __restrict__ outB) {
  const int z = blockIdx.z;
  const int t0 = z ? t0b : t0f;
  const float* __restrict__ W  = z ? Wb  : Wf;
  const float* __restrict__ b1 = z ? b1b : b1f;
  const float* __restrict__ b2 = z ? b2b : b2f;
  float* __restrict__ Cc = z ? outB : outF;

  __shared__ float As[16][128];
  __shared__ float Bs[16][128];
  const int tid = threadIdx.x;
  const int bm = blockIdx.y * 128;
  const int bn = blockIdx.x * 128;
  const int tx = tid & 15;
  const int ty = tid >> 4;

  float acc[8][8];
  #pragma unroll
  for (int i = 0; i < 8; ++i)
    #pragma unroll
    for (int j = 0; j < 8; ++j) acc[i][j] = 0.f;

  for (int k0 = 0; k0 < D_; k0 += 16) {
    #pragma unroll
    for (int s = tid; s < 512; s += 256) {
      int r = s >> 2, k4 = (s & 3) * 4;
      int rl = bm + r;
      const float* arow = A + ((size_t)(rl >> 6) * T_ + t0 + (rl & 63)) * D_;
      float4 va = *(const float4*)(arow + k0 + k4);
      As[k4 + 0][r] = va.x; As[k4 + 1][r] = va.y;
      As[k4 + 2][r] = va.z; As[k4 + 3][r] = va.w;
      float4 vb = *(const float4*)(W + (size_t)(bn + r) * D_ + k0 + k4);
      Bs[k4 + 0][r] = vb.x; Bs[k4 + 1][r] = vb.y;
      Bs[k4 + 2][r] = vb.z; Bs[k4 + 3][r] = vb.w;
    }
    __syncthreads();
    #pragma unroll
    for (int k = 0; k < 16; ++k) {
      float a[8], bv[8];
      *(float4*)(a)      = *(const float4*)&As[k][ty * 4];
      *(float4*)(a + 4)  = *(const float4*)&As[k][64 + ty * 4];
      *(float4*)(bv)     = *(const float4*)&Bs[k][tx * 4];
      *(float4*)(bv + 4) = *(const float4*)&Bs[k][64 + tx * 4];
      #pragma unroll
      for (int i = 0; i < 8; ++i)
        #pragma unroll
        for (int j = 0; j < 8; ++j)
          acc[i][j] += a[i] * bv[j];
    }
    __syncthreads();
  }

  float4 b1l = *(const float4*)(b1 + bn + tx * 4);
  float4 b2l = *(const float4*)(b2 + bn + tx * 4);
  float4 b1h = *(const float4*)(b1 + bn + 64 + tx * 4);
  float4 b2h = *(const float4*)(b2 + bn + 64 + tx * 4);
  float4 bl = {b1l.x + b2l.x, b1l.y + b2l.y, b1l.z + b2l.z, b1l.w + b2l.w};
  float4 bh = {b1h.x + b2h.x, b1h.y + b2h.y, b1h.z + b2h.z, b1h.w + b2h.w};

  #pragma unroll
  for (int i = 0; i < 8; ++i) {
    int r = (i < 4) ? (ty * 4 + i) : (64 + ty * 4 + (i - 4));
    size_t row = (size_t)(bm + r);
    float4 lo = {acc[i][0] + bl.x, acc[i][1] + bl.y, acc[i][2] + bl.z, acc[i][3] + bl.w};
    float4 hi = {acc[i][4] + bh.x, acc[i][5] + bh.y, acc[i][6] + bh.z, acc[i][7] + bh.w};
    *(float4*)(Cc + row * G4 + bn + tx * 4)      = lo;
    *(float4*)(Cc + row * G4 + bn + 64 + tx * 4) = hi;
  }
}

// ---- per-half matvec + butterfly + gate-LDS write (8 batches) --------------
__device__ __forceinline__ void half_step(const float* __restrict__ hlds,
                                          float* __restrict__ gdst,
                                          const float4 (&W)[3][6],
                                          int g, int kg, int uq) {
  float acc[3][8];
  #pragma unroll
  for (int i = 0; i < 3; ++i)
    #pragma unroll
    for (int b = 0; b < 8; ++b) acc[i][b] = 0.f;

  const int hcol = kg * 28;
  #pragma unroll
  for (int kq = 0; kq < 6; ++kq) {
    float4 h4[8];
    #pragma unroll
    for (int bb = 0; bb < 8; ++bb)
      h4[bb] = *(const float4*)&hlds[bb * 448 + hcol + kq * 4];
    #pragma unroll
    for (int i = 0; i < 3; ++i) {
      float4 w4 = W[i][kq];
      #pragma unroll
      for (int bb = 0; bb < 8; ++bb)
        acc[i][bb] += w4.x * h4[bb].x + w4.y * h4[bb].y
                    + w4.z * h4[bb].z + w4.w * h4[bb].w;
    }
  }

  // butterfly over kg bits {8,4,2}: 8 values -> 1 per lane (pair-duplicated)
  float red[3];
  #pragma unroll
  for (int i = 0; i < 3; ++i) {
    int n = 8;
    #pragma unroll
    for (int mask = 8; mask >= 2; mask >>= 1) {
      n >>= 1;
      const bool up = (kg & mask) != 0;
      #pragma unroll
      for (int j = 0; j < n; ++j) {
        float send = up ? acc[i][j] : acc[i][j + n];
        float recv = __shfl_xor(send, mask, 64);
        acc[i][j] = (up ? acc[i][j + n] : acc[i][j]) + recv;
      }
    }
    red[i] = acc[i][0] + __shfl_xor(acc[i][0], 1, 64);
  }

  if ((kg & 1) == 0) {
    const int bsel = ((kg >> 3) & 1) * 4 + ((kg >> 2) & 1) * 2 + ((kg >> 1) & 1);
    gdst[g * 96 + (uq * 3 + 0) * 8 + bsel] = red[0];
    gdst[g * 96 + (uq * 3 + 1) * 8 + bsel] = red[1];
    gdst[g * 96 + (uq * 3 + 2) * 8 + bsel] = red[2];
  }
}

// ---------------- persistent-W LSTM recurrence chunk ------------------------
// 256 WGs (1/CU). stream = bid&7 -> (dir, 16-batch group); wg = bid>>3 -> 12
// hidden units, W in VGPRs. Batches split into halves P(0..7)/Q(8..15) and
// software-pipelined so IC latency hides under the other half's compute.
// All cross-WG exchange: sc0 sc1 stores/loads + flag spin (round-4 verified).
template<int LAYER>
__global__ __launch_bounds__(256, 1)
void lstm_chunk(const float* __restrict__ preF, const float* __restrict__ preB,
                const float* __restrict__ whhF, const float* __restrict__ whhB,
                float* __restrict__ hbuf, float* __restrict__ h2cF, float* __restrict__ h2cB,
                float* __restrict__ h_g, float* __restrict__ c_g,
                unsigned* __restrict__ flags, int chunk, unsigned seqBase) {
  const int bid    = blockIdx.x;
  const int stream = bid & 7;
  const int wg     = bid >> 3;          // 0..31
  const int dir    = stream & 1;
  const int bg     = stream >> 1;       // 0..3
  const int tid    = threadIdx.x;
  const int g      = tid >> 6;          // gate 0..3
  const int lane   = tid & 63;
  const int kg     = lane & 15;         // k-slice id (24 k each)
  const int uq     = lane >> 4;         // 0..3

  const float* __restrict__ pre = dir ? preB : preF;
  const float* __restrict__ whh = dir ? whhB : whhF;

  __shared__ float hP_lds[8 * 448];
  __shared__ float hQ_lds[8 * 448];
  __shared__ float gP[384];
  __shared__ float gQ[384];
  __shared__ float lds_pad[12800];      // force 1 WG/CU

  if (flags[511] == 0xDEADBEEFu) lds_pad[tid] = 1.f;  // keep pad alive

  // ---- W block in registers: rows g*384 + wg*12 + uq*3 + {0,1,2}, k = kg*24.. ----
  float4 W[3][6];
  {
    const float* wsrc = whh + ((size_t)(g * H_ + wg * 12 + uq * 3)) * H_ + kg * 24;
    #pragma unroll
    for (int i = 0; i < 3; ++i)
      #pragma unroll
      for (int jj = 0; jj < 6; ++jj)
        W[i][jj] = *(const float4*)(wsrc + (size_t)i * H_ + jj * 4);
  }

  // nonlinearity ownership: tid<96 -> (u = tid%12, b = tid/12 in [0,8))
  const int own_u = tid % 12;
  const int own_b = tid / 12;
  float cP = 0.f, cQ = 0.f;
  if (chunk > 0 && tid < 96) {
    cP = c_g[(((size_t)stream * 32 + wg) * 12 + own_u) * 16 + own_b];
    cQ = c_g[(((size_t)stream * 32 + wg) * 12 + own_u) * 16 + 8 + own_b];
  }

  // h exchange regions: (half, parity, stream) -> 8 batches x 384
  float* hgP[2] = { h_g + (size_t)(0 * 8 + stream) * 3072,
                    h_g + (size_t)(1 * 8 + stream) * 3072 };
  float* hgQ[2] = { h_g + (size_t)(2 * 8 + stream) * 3072,
                    h_g + (size_t)(3 * 8 + stream) * 3072 };
  unsigned* flagsP = flags;
  unsigned* flagsQ = flags + 256;

  // ---- init h_lds (swizzle col = (k/24)*28 + k%24); cross-launch: plain ----
  if (chunk == 0) {
    for (int i = tid; i < 8 * 448; i += 256) { hP_lds[i] = 0.f; hQ_lds[i] = 0.f; }
  } else {
    #pragma unroll
    for (int i = 0; i < 3; ++i) {
      int f = tid + i * 256;            // float4 index 0..767
      int b = f / 96;
      int k4 = (f % 96) * 4;
      float4 vP = *(const float4*)(hgP[0] + b * 384 + k4);
      float4 vQ = *(const float4*)(hgQ[0] + b * 384 + k4);
      *(float4*)&hP_lds[b * 448 + (k4 / 24) * 28 + (k4 % 24)] = vP;
      *(float4*)&hQ_lds[b * 448 + (k4 / 24) * 28 + (k4 % 24)] = vQ;
    }
  }
  __syncthreads();

  const int ucol = wg * 12;

  for (int s = 0; s < TC; ++s) {
    const int t  = dir ? (T_ - 1 - chunk * TC - s) : (chunk * TC + s);
    const int lt = dir ? (TC - 1 - s) : s;
    const unsigned seq = seqBase + (unsigned)s + 1u;
    const int par = (s + 1) & 1;

    // ================= phase P =================
    float preP0, preP1, preP2, preP3;
    if (tid < 96) {
      const size_t pbase = ((size_t)(bg * 16 + own_b) * TC + lt) * G4 + ucol + own_u;
      preP0 = pre[pbase];           preP1 = pre[pbase + H_];
      preP2 = pre[pbase + 2 * H_];  preP3 = pre[pbase + 3 * H_];
    }
    half_step(hP_lds, gP, W, g, kg, uq);
    __syncthreads();                              // gP ready
    if (tid < 96) {
      float gi = sigm(gP[0 * 96 + own_u * 8 + own_b] + preP0);
      float gf = sigm(gP[1 * 96 + own_u * 8 + own_b] + preP1);
      float gg = tanhf(gP[2 * 96 + own_u * 8 + own_b] + preP2);
      float go = sigm(gP[3 * 96 + own_u * 8 + own_b] + preP3);
      cP = gf * cP + gi * gg;
      float h_new = go * tanhf(cP);
      asm volatile("global_store_dword %0, %1, off sc0 sc1"
                   :: "v"(hgP[par] + own_b * 384 + ucol + own_u), "v"(h_new) : "memory");
      const int bglob = bg * 16 + own_b;
      if (LAYER == 0)
        hbuf[((size_t)bglob * T_ + t) * 768 + dir * H_ + ucol + own_u] = h_new;
      else
        (dir ? h2cB : h2cF)[((size_t)bglob * TC + lt) * H_ + ucol + own_u] = h_new;
    }
    // P stores propagate while Q computes.

    // ================= phase Q =================
    float preQ0, preQ1, preQ2, preQ3;
    if (tid < 96) {
      const size_t pbase = ((size_t)(bg * 16 + 8 + own_b) * TC + lt) * G4 + ucol + own_u;
      preQ0 = pre[pbase];           preQ1 = pre[pbase + H_];
      preQ2 = pre[pbase + 2 * H_];  preQ3 = pre[pbase + 3 * H_];
    }
    half_step(hQ_lds, gQ, W, g, kg, uq);
    asm volatile("s_waitcnt vmcnt(0)" ::: "memory");   // this wave's P stores ack'd
    __syncthreads();                                   // all waves ack'd; gQ ready
    if (tid == 0)
      asm volatile("global_store_dword %0, %1, off sc0 sc1"
                   :: "v"(&flagsP[stream * 32 + wg]), "v"(seq) : "memory");
    if (tid < 96) {
      float gi = sigm(gQ[0 * 96 + own_u * 8 + own_b] + preQ0);
      float gf = sigm(gQ[1 * 96 + own_u * 8 + own_b] + preQ1);
      float gg = tanhf(gQ[2 * 96 + own_u * 8 + own_b] + preQ2);
      float go = sigm(gQ[3 * 96 + own_u * 8 + own_b] + preQ3);
      cQ = gf * cQ + gi * gg;
      float h_new = go * tanhf(cQ);
      asm volatile("global_store_dword %0, %1, off sc0 sc1"
                   :: "v"(hgQ[par] + own_b * 384 + ucol + own_u), "v"(h_new) : "memory");
      const int bglob = bg * 16 + 8 + own_b;
      if (LAYER == 0)
        hbuf[((size_t)bglob * T_ + t) * 768 + dir * H_ + ucol + own_u] = h_new;
      else
        (dir ? h2cB : h2cF)[((size_t)bglob * TC + lt) * H_ + ucol + own_u] = h_new;
    }
    if (s == TC - 1) break;   // next launch reads parity 0 via kernel boundary

    // ---- poll P flags (Q stores propagate under this) ----
    if (tid < 32) {
      const unsigned* fp = &flagsP[stream * 32 + tid];
      unsigned v;
      while (true) {
        asm volatile("global_load_dword %0, %1, off sc0 sc1\n\ts_waitcnt vmcnt(0)"
                     : "=v"(v) : "v"(fp) : "memory");
        if (v >= seq) break;
        __builtin_amdgcn_s_sleep(1);
      }
    }
    asm volatile("s_waitcnt vmcnt(0)" ::: "memory");   // this wave's Q stores ack'd
    __syncthreads();                                   // all waves ack'd
    if (tid == 0)
      asm volatile("global_store_dword %0, %1, off sc0 sc1"
                   :: "v"(&flagsQ[stream * 32 + wg]), "v"(seq) : "memory");

    // ---- reload hP (flagQ propagates under this) ----
    {
      f32x4 tmp[3];
      #pragma unroll
      for (int i = 0; i < 3; ++i) {
        int f = tid + i * 256;
        int b = f / 96;
        int k4 = (f % 96) * 4;
        asm volatile("global_load_dwordx4 %0, %1, off sc0 sc1"
                     : "=v"(tmp[i]) : "v"(hgP[par] + b * 384 + k4) : "memory");
      }
      asm volatile("s_waitcnt vmcnt(0)" ::: "memory");
      __builtin_amdgcn_sched_barrier(0);
      #pragma unroll
      for (int i = 0; i < 3; ++i) {
        int f = tid + i * 256;
        int b = f / 96;
        int k4 = (f % 96) * 4;
        *(f32x4*)&hP_lds[b * 448 + (k4 / 24) * 28 + (k4 % 24)] = tmp[i];
      }
    }
    __syncthreads();                                   // hP ready

    // ---- poll Q flags (stored one reload ago -> quick) + reload hQ ----
    if (tid < 32) {
      const unsigned* fp = &flagsQ[stream * 32 + tid];
      unsigned v;
      while (true) {
        asm volatile("global_load_dword %0, %1, off sc0 sc1\n\ts_waitcnt vmcnt(0)"
                     : "=v"(v) : "v"(fp) : "memory");
        if (v >= seq) break;
        __builtin_amdgcn_s_sleep(1);
      }
    }
    __syncthreads();
    {
      f32x4 tmp[3];
      #pragma unroll
      for (int i = 0; i < 3; ++i) {
        int f = tid + i * 256;
        int b = f / 96;
        int k4 = (f % 96) * 4;
        asm volatile("global_load_dwordx4 %0, %1, off sc0 sc1"
                     : "=v"(tmp[i]) : "v"(hgQ[par] + b * 384 + k4) : "memory");
      }
      asm volatile("s_waitcnt vmcnt(0)" ::: "memory");
      __builtin_amdgcn_sched_barrier(0);
      #pragma unroll
      for (int i = 0; i < 3; ++i) {
        int f = tid + i * 256;
        int b = f / 96;
        int k4 = (f % 96) * 4;
        *(f32x4*)&hQ_lds[b * 448 + (k4 / 24) * 28 + (k4 % 24)] = tmp[i];
      }
    }
    __syncthreads();                                   // hQ ready
  }

  if (tid < 96) {
    c_g[(((size_t)stream * 32 + wg) * 12 + own_u) * 16 + own_b]     = cP;
    c_g[(((size_t)stream * 32 + wg) * 12 + own_u) * 16 + 8 + own_b] = cQ;
  }
}

// ---------------- feats init: feats[row][n] = fc_b[n] ------------------------
__global__ __launch_bounds__(256)
void feats_init(const float* __restrict__ fc_b, float* __restrict__ feats) {
  const int n = threadIdx.x & 31;
  const size_t row = (size_t)blockIdx.x * 8 + (threadIdx.x >> 5);
  if (n >= NTAGS) return;
  feats[row * NTAGS + n] = fc_b[n];
}

// -------- half-FC accumulate (z picks fwd/bwd): feats += h2c @ fc_w_half^T ---
__global__ __launch_bounds__(256)
void fc_half(const float* __restrict__ h2cF, const float* __restrict__ h2cB,
             const float* __restrict__ fc_w,
             float* __restrict__ feats, int t0f, int t0b) {
  const int z = blockIdx.z;
  const float* __restrict__ h2c = z ? h2cB : h2cF;
  const int coff = z ? H_ : 0;
  const int t0   = z ? t0b : t0f;

  const int tid = threadIdx.x;
  const int n  = tid & 31;
  const int rl = tid >> 5;
  const int row_loc = blockIdx.x * 8 + rl;     // 0..4095
  if (n >= NTAGS) return;
  const int b  = row_loc >> 6;
  const int lt = row_loc & 63;
  const float* x = h2c + (size_t)row_loc * H_;
  const float* w = fc_w + (size_t)n * D_ + coff;
  float acc = 0.f;
  #pragma unroll 8
  for (int k = 0; k < H_; k += 4) {
    float4 xv = *(const float4*)(x + k);
    float4 wv = *(const float4*)(w + k);
    acc += xv.x * wv.x + xv.y * wv.y + xv.z * wv.z + xv.w * wv.w;
  }
  feats[((size_t)b * T_ + t0 + lt) * NTAGS + n] += acc;
}

// ---------------- Viterbi: one wave per batch element -----------------------
__global__ __launch_bounds__(64)
void viterbi_kernel(const float* __restrict__ feats,
                    const float* __restrict__ trans,
                    float* __restrict__ score_out, float* __restrict__ path_out) {
  const int b = blockIdx.x;
  const int lane = threadIdx.x;
  __shared__ float trs[NTAGS * NTAGS];
  __shared__ float ld[32];
  __shared__ unsigned char psi[T_ - 1][NTAGS];

  for (int i = lane; i < NTAGS * NTAGS; i += 64) trs[i] = trans[i];
  if (lane < NTAGS) ld[lane] = -10000.0f;
  __syncthreads();

  for (int t = 1; t < T_; ++t) {
    float best = -INFINITY; int arg = 0;
    if (lane < NTAGS) {
      #pragma unroll
      for (int p = 0; p < NTAGS; ++p) {
        float v = trs[lane * NTAGS + p] + ld[p];
        if (v > best) { best = v; arg = p; }   // first-occurrence argmax
      }
    }
    __syncthreads();
    if (lane < NTAGS) {
      ld[lane] = best + feats[((size_t)b * T_ + t) * NTAGS + lane];
      psi[t - 1][lane] = (unsigned char)arg;
    }
    __syncthreads();
  }

  if (lane == 0) {
    float best = ld[0]; int last = 0;
    #pragma unroll
    for (int p = 1; p < NTAGS; ++p)
      if (ld[p] > best) { best = ld[p]; last = p; }
    score_out[b] = best;
    int tag = last;
    path_out[(size_t)b * T_ + (T_ - 1)] = (float)tag;
    for (int t = T_ - 2; t >= 0; --t) {
      tag = psi[t][tag];
      path_out[(size_t)b * T_ + t] = (float)tag;
    }
  }
}

// ---------------------------------------------------------------------------
extern "C" void kernel_launch(void* const* d_in, const int* in_sizes, int n_in,
                              void* d_out, int out_size, void* d_ws, size_t ws_size,
                              hipStream_t stream) {
  const float* embeds = (const float*)d_in[0];
  const float* trans  = (const float*)d_in[1];
  const float* fc_w   = (const float*)d_in[2];
  const float* fc_b   = (const float*)d_in[3];
  const float* w_ih[2][2] = {{(const float*)d_in[4],  (const float*)d_in[8]},
                             {(const float*)d_in[12], (const float*)d_in[16]}};
  const float* w_hh[2][2] = {{(const float*)d_in[5],  (const float*)d_in[9]},
                             {(const float*)d_in[13], (const float*)d_in[17]}};
  const float* b_ih[2][2] = {{(const float*)d_in[6],  (const float*)d_in[10]},
                             {(const float*)d_in[14], (const float*)d_in[18]}};
  const float* b_hh[2][2] = {{(const float*)d_in[7],  (const float*)d_in[11]},
                             {(const float*)d_in[15], (const float*)d_in[19]}};

  const size_t HB   = (size_t)B_ * T_ * 768;     // 25,165,824 (h1)
  const size_t PRE  = (size_t)B_ * TC * G4;      //  6,291,456 each
  const size_t H2C  = (size_t)B_ * TC * H_;      //  1,572,864 each
  const size_t FT   = (size_t)B_ * T_ * NTAGS;   //    983,040
  const size_t HG   = (size_t)4 * 8 * 3072;      //     98,304
  const size_t CG   = (size_t)8 * 32 * 12 * 16;  //     49,152

  float* ws     = (float*)d_ws;
  float* hbuf   = ws;
  float* preF   = hbuf + HB;
  float* preB   = preF + PRE;
  float* h2cF   = preB + PRE;
  float* h2cB   = h2cF + H2C;
  float* feats  = h2cB + H2C;
  float* h_g    = feats + FT;
  float* c_g    = h_g + HG;
  unsigned* flags = (unsigned*)(c_g + CG);       // 512 u32 (P:0..255, Q:256..511)

  hipMemsetAsync(flags, 0, 512 * sizeof(unsigned), stream);
  feats_init<<<(B_ * T_) / 8, 256, 0, stream>>>(fc_b, feats);

  dim3 gg(G4 / 128, (B_ * TC) / 128, 2);         // (12, 32, 2) = 768 WGs

  // -------- layer 0 --------
  for (int c = 0; c < NCH; ++c) {
    const int t0f = c * TC;
    const int t0b = T_ - (c + 1) * TC;
    sgemm_pre<<<gg, 256, 0, stream>>>(embeds, t0f, t0b, w_ih[0][0], w_ih[0][1],
                                      b_ih[0][0], b_hh[0][0], b_ih[0][1], b_hh[0][1],
                                      preF, preB);
    lstm_chunk<0><<<256, 256, 0, stream>>>(preF, preB, w_hh[0][0], w_hh[0][1],
                                           hbuf, nullptr, nullptr, h_g, c_g,
                                           flags, c, (unsigned)(c * TC));
  }

  // -------- layer 1 (+ per-chunk half-FC) --------
  for (int c = 0; c < NCH; ++c) {
    const int t0f = c * TC;
    const int t0b = T_ - (c + 1) * TC;
    sgemm_pre<<<gg, 256, 0, stream>>>(hbuf, t0f, t0b, w_ih[1][0], w_ih[1][1],
                                      b_ih[1][0], b_hh[1][0], b_ih[1][1], b_hh[1][1],
                                      preF, preB);
    lstm_chunk<1><<<256, 256, 0, stream>>>(preF, preB, w_hh[1][0], w_hh[1][1],
                                           nullptr, h2cF, h2cB, h_g, c_g,
                                           flags, c, (unsigned)(T_ + c * TC));
    dim3 gf((B_ * TC) / 8, 1, 2);
    fc_half<<<gf, 256, 0, stream>>>(h2cF, h2cB, fc_w, feats, t0f, t0b);
  }

  // -------- Viterbi -> d_out = [score(64) | path(64*512) as float] --------
  float* score = (float*)d_out;
  float* path  = score + B_;
  viterbi_kernel<<<B_, 64, 0, stream>>>(feats, trans, score, path);
}